// Round 7
// baseline (338.877 us; speedup 1.0000x reference)
//
#include <hip/hip_runtime.h>

#define Bn 1024
#define Tn 256

typedef __attribute__((ext_vector_type(4))) float f32x4;
typedef __attribute__((ext_vector_type(2))) float f32x2;
typedef __attribute__((ext_vector_type(8))) short short8;

static __device__ __forceinline__ unsigned pack_bf16_2(float lo, float hi) {
    unsigned ul = __float_as_uint(lo), uh = __float_as_uint(hi);
    ul = (ul + 0x7fffu + ((ul >> 16) & 1u)) >> 16;
    uh = (uh + 0x7fffu + ((uh >> 16) & 1u)) >> 16;
    return (ul & 0xffffu) | (uh << 16);
}

static __device__ __forceinline__ unsigned short f2bf(float f) {
    unsigned u = __float_as_uint(f);
    return (unsigned short)((u + 0x7fffu + ((u >> 16) & 1u)) >> 16);
}

__launch_bounds__(512, 2)
__global__ void bandit_rnn(const float* __restrict__ x,
                           const float* __restrict__ Wxr, const float* __restrict__ Wxz, const float* __restrict__ Wxn,
                           const float* __restrict__ Whr, const float* __restrict__ Whz, const float* __restrict__ Whn,
                           const float* __restrict__ bxr, const float* __restrict__ bxz, const float* __restrict__ bxn,
                           const float* __restrict__ brh, const float* __restrict__ bzh, const float* __restrict__ bnh,
                           const float* __restrict__ Wout, const float* __restrict__ bout,
                           float* __restrict__ out) {
    // comb tables: expert stride 129 f32x4 -> bank shift 4/expert (<=2-way conflicts)
    __shared__ f32x4 comb0[516], comb1[516], comb2[516];
    __shared__ float combB[516];
    // h16 chain stride 144 shorts -> chains on disjoint bank quads (2-way max on b128)
    __shared__ __align__(16) unsigned short h16[2][4][144];
    __shared__ float xs[2][4][3];
    __shared__ unsigned modesArr[Tn];

    const int tid = threadIdx.x;
    const int w = tid >> 6;       // 8 waves
    const int lane = tid & 63;
    const int r16 = lane & 15, q = lane >> 4;
    const int cb = blockIdx.x * 4;
    const int grow = 16 * w + r16;   // this lane's A-row (M index)

    // ---------------- prologue ----------------
    for (int p = tid; p < 2 * 4 * 144; p += 512) ((unsigned short*)h16)[p] = 0;
    {
        int p = tid;              // 512 threads == 512 table rows
        int k = p >> 7, i = p & 127;
        int d = k * 129 + i;
        const float* wr = Wxr + (k * 128 + i) * 3;
        const float* wz = Wxz + (k * 128 + i) * 3;
        const float* wn = Wxn + (k * 128 + i) * 3;
        comb0[d] = (f32x4){wr[0], wr[1], wr[2], bxr[p] + brh[p]};
        comb1[d] = (f32x4){wz[0], wz[1], wz[2], bxz[p] + bzh[p]};
        comb2[d] = (f32x4){wn[0], wn[1], wn[2], bxn[p]};
        combB[d] = bnh[p];
    }
    const float b0 = bout[0], b1 = bout[1];

    if (tid < Tn) {               // all mode words (selector depends only on x)
        const float* xp = x + (size_t)cb * (Tn * 3) + tid * 3;
        unsigned mword = 0;
#pragma unroll
        for (int c = 0; c < 4; ++c) {
            float x0 = xp[c * Tn * 3 + 0];
            float x1 = xp[c * Tn * 3 + 1];
            float x2 = xp[c * Tn * 3 + 2];
            unsigned mode = ((x1 > x0) ? 1u : 0u) + ((x2 > 0.5f) ? 2u : 0u);
            mword |= mode << (8 * c);
        }
        modesArr[tid] = mword;
    }
    if (tid < 12) {
        int c = tid / 3, j = tid % 3;
        xs[0][c][j] = x[(size_t)(cb + c) * (Tn * 3) + j];
    }

    // Wh weights: wave w owns rows [16w,16w+16); 48 short8 = 192 AGPR
    short8 Afr[3][4][4];
    {
        const float* Wh[3] = {Whr, Whz, Whn};
#pragma unroll
        for (int g = 0; g < 3; ++g)
#pragma unroll
        for (int e = 0; e < 4; ++e)
#pragma unroll
        for (int kt = 0; kt < 4; ++kt) {
            const float* p = Wh[g] + (((e * 128) + grow) * 128 + 32 * kt + 8 * q);
            float4 a0 = *(const float4*)p;
            float4 a1 = *(const float4*)(p + 4);
            union { short8 s; unsigned u[4]; } fr;
            fr.u[0] = pack_bf16_2(a0.x, a0.y);
            fr.u[1] = pack_bf16_2(a0.z, a0.w);
            fr.u[2] = pack_bf16_2(a1.x, a1.y);
            fr.u[3] = pack_bf16_2(a1.z, a1.w);
            Afr[g][e][kt] = fr.s;
        }
    }
    // logit fragments: A rows 0,1 = Wout (16 AGPR, identical on every wave)
    short8 Aout[4];
#pragma unroll
    for (int kt = 0; kt < 4; ++kt) {
        union { short8 s; unsigned u[4]; } fr;
        fr.u[0] = fr.u[1] = fr.u[2] = fr.u[3] = 0;
        if (r16 < 2) {
            const float* wp = Wout + r16 * 128 + 32 * kt + 8 * q;
            fr.u[0] = pack_bf16_2(wp[0], wp[1]);
            fr.u[1] = pack_bf16_2(wp[2], wp[3]);
            fr.u[2] = pack_bf16_2(wp[4], wp[5]);
            fr.u[3] = pack_bf16_2(wp[6], wp[7]);
        }
        Aout[kt] = fr.s;
    }

    // per-lane nonlin assignment: chain cc = r16&3, local row j* = r16>>2
    const int cc = r16 & 3;
    const bool jb0 = ((r16 >> 2) & 1) != 0;
    const bool jb1 = ((r16 >> 2) & 2) != 0;
    const int row = 16 * w + 4 * q + (r16 >> 2);
    float hpv = 0.f;              // f32 recurrent state (1 per lane)
    const f32x4 zacc = (f32x4){0.f, 0.f, 0.f, 0.f};
    __syncthreads();

    // ---------------- time loop: ONE barrier per step ----------------
#pragma unroll 1
    for (int t = 0; t < Tn; ++t) {
        const int tb = t & 1;
        // x_{t+1} prefetch on wave 7 (load issued before MFMAs, LDS write after)
        float xpre = 0.f; int xc = 0, xj = 0;
        const bool xload = (t + 1 < Tn) && (w == 7) && (lane < 12);
        if (xload) {
            xc = lane / 3; xj = lane % 3;
            xpre = x[(size_t)(cb + xc) * (Tn * 3) + (t + 1) * 3 + xj];
        }

        const unsigned m = modesArr[t];
        const unsigned pres = (1u << (m & 3)) | (1u << ((m >> 8) & 3)) |
                              (1u << ((m >> 16) & 3)) | (1u << ((m >> 24) & 3));
        const int mode_c = (m >> (8 * cc)) & 3;

        short8 Bf[4];
#pragma unroll
        for (int kt = 0; kt < 4; ++kt)
            Bf[kt] = *(const short8*)&h16[tb][cc][32 * kt + 8 * q];

        // logits of step t-1 via MFMA on this step's Bf (= h after step t-1);
        // rotates across waves so no single wave is the permanent straggler.
        if (t > 0 && w == (t & 7)) {
            f32x4 alg = __builtin_amdgcn_mfma_f32_16x16x32_bf16(Aout[0], Bf[0], zacc, 0, 0, 0);
#pragma unroll
            for (int kt = 1; kt < 4; ++kt)
                alg = __builtin_amdgcn_mfma_f32_16x16x32_bf16(Aout[kt], Bf[kt], alg, 0, 0, 0);
            if (lane < 4)
                *(f32x2*)&out[((size_t)(cb + lane) * Tn + (t - 1)) * 2] =
                    (f32x2){alg[0] + b0, alg[1] + b1};
        }

        float selR = 0.f, selZ = 0.f, selN = 0.f;
#pragma unroll
        for (int e = 0; e < 4; ++e) {
            if (!(pres & (1u << e))) continue;   // block-uniform skip
            // first MFMA reads the shared zero quad as C (no per-expert acc init)
            f32x4 aR = __builtin_amdgcn_mfma_f32_16x16x32_bf16(Afr[0][e][0], Bf[0], zacc, 0, 0, 0);
            f32x4 aZ = __builtin_amdgcn_mfma_f32_16x16x32_bf16(Afr[1][e][0], Bf[0], zacc, 0, 0, 0);
            f32x4 aN = __builtin_amdgcn_mfma_f32_16x16x32_bf16(Afr[2][e][0], Bf[0], zacc, 0, 0, 0);
#pragma unroll
            for (int kt = 1; kt < 4; ++kt) {
                aR = __builtin_amdgcn_mfma_f32_16x16x32_bf16(Afr[0][e][kt], Bf[kt], aR, 0, 0, 0);
                aZ = __builtin_amdgcn_mfma_f32_16x16x32_bf16(Afr[1][e][kt], Bf[kt], aZ, 0, 0, 0);
                aN = __builtin_amdgcn_mfma_f32_16x16x32_bf16(Afr[2][e][kt], Bf[kt], aN, 0, 0, 0);
            }
            // per-lane scalar select of element j* = r16>>2, then mode-match select
            float vR = jb1 ? (jb0 ? aR[3] : aR[2]) : (jb0 ? aR[1] : aR[0]);
            float vZ = jb1 ? (jb0 ? aZ[3] : aZ[2]) : (jb0 ? aZ[1] : aZ[0]);
            float vN = jb1 ? (jb0 ? aN[3] : aN[2]) : (jb0 ? aN[1] : aN[0]);
            bool mym = (mode_c == e);
            selR = mym ? vR : selR;
            selZ = mym ? vZ : selZ;
            selN = mym ? vN : selN;
        }
        if (xload) xs[tb ^ 1][xc][xj] = xpre;

        // fused nonlinearity: lane owns (chain cc, row)
        {
            const int d = mode_c * 129 + row;
            float x0 = xs[tb][cc][0], x1 = xs[tb][cc][1], x2 = xs[tb][cc][2];
            f32x4 c0 = comb0[d];
            f32x4 c1 = comb1[d];
            f32x4 c2 = comb2[d];
            float bn = combB[d];
            float rp = selR + c0[3] + c0[0] * x0 + c0[1] * x1 + c0[2] * x2;
            float zp = selZ + c1[3] + c1[0] * x0 + c1[1] * x1 + c1[2] * x2;
            float xn =        c2[3] + c2[0] * x0 + c2[1] * x1 + c2[2] * x2;
            float r = __builtin_amdgcn_rcpf(1.f + __expf(-rp));
            float z = __builtin_amdgcn_rcpf(1.f + __expf(-zp));
            float npv = xn + r * (selN + bn);
            float ex = __expf(2.f * npv);
            float n = 1.f - 2.f * __builtin_amdgcn_rcpf(ex + 1.f);
            float h = n + z * (hpv - n);
            hpv = h;
            h16[tb ^ 1][cc][row] = f2bf(h);
        }
        __syncthreads();
    }

    // epilogue: logits of t = Tn-1 from h16[Tn&1] (holds final h)
    if (w == 0) {
        f32x4 alg = zacc;
#pragma unroll
        for (int kt = 0; kt < 4; ++kt) {
            short8 bfe = *(const short8*)&h16[Tn & 1][cc][32 * kt + 8 * q];
            alg = __builtin_amdgcn_mfma_f32_16x16x32_bf16(Aout[kt], bfe, alg, 0, 0, 0);
        }
        if (lane < 4)
            *(f32x2*)&out[((size_t)(cb + lane) * Tn + (Tn - 1)) * 2] =
                (f32x2){alg[0] + b0, alg[1] + b1};
    }
    // final hidden state hT from registers (one element per lane)
    out[(size_t)Bn * Tn * 2 + (size_t)(cb + cc) * 128 + row] = hpv;
}

extern "C" void kernel_launch(void* const* d_in, const int* in_sizes, int n_in,
                              void* d_out, int out_size, void* d_ws, size_t ws_size,
                              hipStream_t stream) {
    const float* xin = (const float*)d_in[0];
    const float* Wxr = (const float*)d_in[1];
    const float* Wxz = (const float*)d_in[2];
    const float* Wxn = (const float*)d_in[3];
    const float* Whr = (const float*)d_in[4];
    const float* Whz = (const float*)d_in[5];
    const float* Whn = (const float*)d_in[6];
    const float* bxr = (const float*)d_in[7];
    const float* bxz = (const float*)d_in[8];
    const float* bxn = (const float*)d_in[9];
    const float* brh = (const float*)d_in[10];
    const float* bzh = (const float*)d_in[11];
    const float* bnh = (const float*)d_in[12];
    const float* Wout = (const float*)d_in[13];
    const float* bout = (const float*)d_in[14];
    float* outp = (float*)d_out;

    hipLaunchKernelGGL(bandit_rnn, dim3(256), dim3(512), 0, stream,
                       xin, Wxr, Wxz, Wxn, Whr, Whz, Whn,
                       bxr, bxz, bxn, brh, bzh, bnh, Wout, bout, outp);
}

// Round 8
// 294.357 us; speedup vs baseline: 1.1512x; 1.1512x over previous
//
#include <hip/hip_runtime.h>

#define Bn 1024
#define Tn 256

typedef __attribute__((ext_vector_type(4))) float f32x4;
typedef __attribute__((ext_vector_type(2))) float f32x2;
typedef __attribute__((ext_vector_type(8))) short short8;

static __device__ __forceinline__ unsigned pack_bf16_2(float lo, float hi) {
    unsigned ul = __float_as_uint(lo), uh = __float_as_uint(hi);
    ul = (ul + 0x7fffu + ((ul >> 16) & 1u)) >> 16;
    uh = (uh + 0x7fffu + ((uh >> 16) & 1u)) >> 16;
    return (ul & 0xffffu) | (uh << 16);
}

static __device__ __forceinline__ unsigned short f2bf(float f) {
    unsigned u = __float_as_uint(f);
    return (unsigned short)((u + 0x7fffu + ((u >> 16) & 1u)) >> 16);
}

__launch_bounds__(512, 2)
__global__ void bandit_rnn(const float* __restrict__ x,
                           const float* __restrict__ Wxr, const float* __restrict__ Wxz, const float* __restrict__ Wxn,
                           const float* __restrict__ Whr, const float* __restrict__ Whz, const float* __restrict__ Whn,
                           const float* __restrict__ bxr, const float* __restrict__ bxz, const float* __restrict__ bxn,
                           const float* __restrict__ brh, const float* __restrict__ bzh, const float* __restrict__ bnh,
                           const float* __restrict__ Wout, const float* __restrict__ bout,
                           float* __restrict__ out) {
    // comb tables: expert stride 129 f32x4 -> bank shift 4/expert (<=2-way conflicts)
    __shared__ f32x4 comb0[516], comb1[516], comb2[516];
    __shared__ float combB[516];
    // h16 chain stride 144 shorts -> (cc,q) address groups all exactly 2-way
    __shared__ __align__(16) unsigned short h16[2][4][144];
    __shared__ float xs[2][4][3];
    __shared__ unsigned modesArr[Tn];
    // Wout MFMA fragments live in LDS (NOT registers: 16 extra AGPRs on every
    // wave pushed the 256-reg/thread budget over -> 1-dword/step scratch spill)
    __shared__ __align__(16) short8 aoutL[4][64];

    const int tid = threadIdx.x;
    const int w = tid >> 6;       // 8 waves
    const int lane = tid & 63;
    const int r16 = lane & 15, q = lane >> 4;
    const int cb = blockIdx.x * 4;
    const int grow = 16 * w + r16;   // this lane's A-row (M index)

    // ---------------- prologue ----------------
    for (int p = tid; p < 2 * 4 * 144; p += 512) ((unsigned short*)h16)[p] = 0;
    {
        int p = tid;              // 512 threads == 512 table rows
        int k = p >> 7, i = p & 127;
        int d = k * 129 + i;
        const float* wr = Wxr + (k * 128 + i) * 3;
        const float* wz = Wxz + (k * 128 + i) * 3;
        const float* wn = Wxn + (k * 128 + i) * 3;
        comb0[d] = (f32x4){wr[0], wr[1], wr[2], bxr[p] + brh[p]};
        comb1[d] = (f32x4){wz[0], wz[1], wz[2], bxz[p] + bzh[p]};
        comb2[d] = (f32x4){wn[0], wn[1], wn[2], bxn[p]};
        combB[d] = bnh[p];
    }
    const float b0 = bout[0], b1 = bout[1];

    if (tid < Tn) {               // all mode words (selector depends only on x)
        const float* xp = x + (size_t)cb * (Tn * 3) + tid * 3;
        unsigned mword = 0;
#pragma unroll
        for (int c = 0; c < 4; ++c) {
            float x0 = xp[c * Tn * 3 + 0];
            float x1 = xp[c * Tn * 3 + 1];
            float x2 = xp[c * Tn * 3 + 2];
            unsigned mode = ((x1 > x0) ? 1u : 0u) + ((x2 > 0.5f) ? 2u : 0u);
            mword |= mode << (8 * c);
        }
        modesArr[tid] = mword;
    }
    if (tid < 12) {
        int c = tid / 3, j = tid % 3;
        xs[0][c][j] = x[(size_t)(cb + c) * (Tn * 3) + j];
    }
    if (tid < 64) {               // Wout fragments, lane-indexed (same for all waves)
#pragma unroll
        for (int kt = 0; kt < 4; ++kt) {
            union { short8 s; unsigned u[4]; } fr;
            fr.u[0] = fr.u[1] = fr.u[2] = fr.u[3] = 0;
            if (r16 < 2) {
                const float* wp = Wout + r16 * 128 + 32 * kt + 8 * q;
                fr.u[0] = pack_bf16_2(wp[0], wp[1]);
                fr.u[1] = pack_bf16_2(wp[2], wp[3]);
                fr.u[2] = pack_bf16_2(wp[4], wp[5]);
                fr.u[3] = pack_bf16_2(wp[6], wp[7]);
            }
            aoutL[kt][lane] = fr.s;
        }
    }

    // Wh weights: wave w owns rows [16w,16w+16); 48 short8 = 192 AGPR
    short8 Afr[3][4][4];
    {
        const float* Wh[3] = {Whr, Whz, Whn};
#pragma unroll
        for (int g = 0; g < 3; ++g)
#pragma unroll
        for (int e = 0; e < 4; ++e)
#pragma unroll
        for (int kt = 0; kt < 4; ++kt) {
            const float* p = Wh[g] + (((e * 128) + grow) * 128 + 32 * kt + 8 * q);
            float4 a0 = *(const float4*)p;
            float4 a1 = *(const float4*)(p + 4);
            union { short8 s; unsigned u[4]; } fr;
            fr.u[0] = pack_bf16_2(a0.x, a0.y);
            fr.u[1] = pack_bf16_2(a0.z, a0.w);
            fr.u[2] = pack_bf16_2(a1.x, a1.y);
            fr.u[3] = pack_bf16_2(a1.z, a1.w);
            Afr[g][e][kt] = fr.s;
        }
    }

    // per-lane nonlin assignment: chain cc = r16&3, local row j* = r16>>2
    const int cc = r16 & 3;
    const bool jb0 = ((r16 >> 2) & 1) != 0;
    const bool jb1 = ((r16 >> 2) & 2) != 0;
    const int row = 16 * w + 4 * q + (r16 >> 2);
    float hpv = 0.f;              // f32 recurrent state (1 per lane)
    const f32x4 zacc = (f32x4){0.f, 0.f, 0.f, 0.f};
    __syncthreads();

    // ---------------- time loop: ONE barrier per step ----------------
#pragma unroll 1
    for (int t = 0; t < Tn; ++t) {
        const int tb = t & 1;
        // x_{t+1} prefetch on wave 7 (load issued before MFMAs, LDS write after)
        float xpre = 0.f; int xc = 0, xj = 0;
        const bool xload = (t + 1 < Tn) && (w == 7) && (lane < 12);
        if (xload) {
            xc = lane / 3; xj = lane % 3;
            xpre = x[(size_t)(cb + xc) * (Tn * 3) + (t + 1) * 3 + xj];
        }

        const unsigned m = modesArr[t];
        const unsigned pres = (1u << (m & 3)) | (1u << ((m >> 8) & 3)) |
                              (1u << ((m >> 16) & 3)) | (1u << ((m >> 24) & 3));
        const int mode_c = (m >> (8 * cc)) & 3;

        short8 Bf[4];
#pragma unroll
        for (int kt = 0; kt < 4; ++kt)
            Bf[kt] = *(const short8*)&h16[tb][cc][32 * kt + 8 * q];

        // logits of step t-1 via MFMA on this step's Bf (= h after step t-1);
        // rotates across waves; Wout fragments come from LDS (register-budget fix)
        if (t > 0 && w == (t & 7)) {
            f32x4 alg = __builtin_amdgcn_mfma_f32_16x16x32_bf16(aoutL[0][lane], Bf[0], zacc, 0, 0, 0);
#pragma unroll
            for (int kt = 1; kt < 4; ++kt)
                alg = __builtin_amdgcn_mfma_f32_16x16x32_bf16(aoutL[kt][lane], Bf[kt], alg, 0, 0, 0);
            if (lane < 4)
                *(f32x2*)&out[((size_t)(cb + lane) * Tn + (t - 1)) * 2] =
                    (f32x2){alg[0] + b0, alg[1] + b1};
        }

        float selR = 0.f, selZ = 0.f, selN = 0.f;
#pragma unroll
        for (int e = 0; e < 4; ++e) {
            if (!(pres & (1u << e))) continue;   // block-uniform skip
            // first MFMA reads the shared zero quad as C (no per-expert acc init)
            f32x4 aR = __builtin_amdgcn_mfma_f32_16x16x32_bf16(Afr[0][e][0], Bf[0], zacc, 0, 0, 0);
            f32x4 aZ = __builtin_amdgcn_mfma_f32_16x16x32_bf16(Afr[1][e][0], Bf[0], zacc, 0, 0, 0);
            f32x4 aN = __builtin_amdgcn_mfma_f32_16x16x32_bf16(Afr[2][e][0], Bf[0], zacc, 0, 0, 0);
#pragma unroll
            for (int kt = 1; kt < 4; ++kt) {
                aR = __builtin_amdgcn_mfma_f32_16x16x32_bf16(Afr[0][e][kt], Bf[kt], aR, 0, 0, 0);
                aZ = __builtin_amdgcn_mfma_f32_16x16x32_bf16(Afr[1][e][kt], Bf[kt], aZ, 0, 0, 0);
                aN = __builtin_amdgcn_mfma_f32_16x16x32_bf16(Afr[2][e][kt], Bf[kt], aN, 0, 0, 0);
            }
            // per-lane scalar select of element j* = r16>>2, then mode-match select
            float vR = jb1 ? (jb0 ? aR[3] : aR[2]) : (jb0 ? aR[1] : aR[0]);
            float vZ = jb1 ? (jb0 ? aZ[3] : aZ[2]) : (jb0 ? aZ[1] : aZ[0]);
            float vN = jb1 ? (jb0 ? aN[3] : aN[2]) : (jb0 ? aN[1] : aN[0]);
            bool mym = (mode_c == e);
            selR = mym ? vR : selR;
            selZ = mym ? vZ : selZ;
            selN = mym ? vN : selN;
        }
        if (xload) xs[tb ^ 1][xc][xj] = xpre;

        // fused nonlinearity: lane owns (chain cc, row)
        {
            const int d = mode_c * 129 + row;
            float x0 = xs[tb][cc][0], x1 = xs[tb][cc][1], x2 = xs[tb][cc][2];
            f32x4 c0 = comb0[d];
            f32x4 c1 = comb1[d];
            f32x4 c2 = comb2[d];
            float bn = combB[d];
            float rp = selR + c0[3] + c0[0] * x0 + c0[1] * x1 + c0[2] * x2;
            float zp = selZ + c1[3] + c1[0] * x0 + c1[1] * x1 + c1[2] * x2;
            float xn =        c2[3] + c2[0] * x0 + c2[1] * x1 + c2[2] * x2;
            float r = __builtin_amdgcn_rcpf(1.f + __expf(-rp));
            float z = __builtin_amdgcn_rcpf(1.f + __expf(-zp));
            float npv = xn + r * (selN + bn);
            float ex = __expf(2.f * npv);
            float n = 1.f - 2.f * __builtin_amdgcn_rcpf(ex + 1.f);
            float h = n + z * (hpv - n);
            hpv = h;
            h16[tb ^ 1][cc][row] = f2bf(h);
        }
        __syncthreads();
    }

    // epilogue: logits of t = Tn-1 from h16[Tn&1] (holds final h)
    if (w == 0) {
        f32x4 alg = zacc;
#pragma unroll
        for (int kt = 0; kt < 4; ++kt) {
            short8 bfe = *(const short8*)&h16[Tn & 1][cc][32 * kt + 8 * q];
            alg = __builtin_amdgcn_mfma_f32_16x16x32_bf16(aoutL[kt][lane], bfe, alg, 0, 0, 0);
        }
        if (lane < 4)
            *(f32x2*)&out[((size_t)(cb + lane) * Tn + (Tn - 1)) * 2] =
                (f32x2){alg[0] + b0, alg[1] + b1};
    }
    // final hidden state hT from registers (one element per lane)
    out[(size_t)Bn * Tn * 2 + (size_t)(cb + cc) * 128 + row] = hpv;
}

extern "C" void kernel_launch(void* const* d_in, const int* in_sizes, int n_in,
                              void* d_out, int out_size, void* d_ws, size_t ws_size,
                              hipStream_t stream) {
    const float* xin = (const float*)d_in[0];
    const float* Wxr = (const float*)d_in[1];
    const float* Wxz = (const float*)d_in[2];
    const float* Wxn = (const float*)d_in[3];
    const float* Whr = (const float*)d_in[4];
    const float* Whz = (const float*)d_in[5];
    const float* Whn = (const float*)d_in[6];
    const float* bxr = (const float*)d_in[7];
    const float* bxz = (const float*)d_in[8];
    const float* bxn = (const float*)d_in[9];
    const float* brh = (const float*)d_in[10];
    const float* bzh = (const float*)d_in[11];
    const float* bnh = (const float*)d_in[12];
    const float* Wout = (const float*)d_in[13];
    const float* bout = (const float*)d_in[14];
    float* outp = (float*)d_out;

    hipLaunchKernelGGL(bandit_rnn, dim3(256), dim3(512), 0, stream,
                       xin, Wxr, Wxz, Wxn, Whr, Whz, Whn,
                       bxr, bxz, bxn, brh, bzh, bnh, Wout, bout, outp);
}